// Round 6
// baseline (233.137 us; speedup 1.0000x reference)
//
#include <hip/hip_runtime.h>

// CapsuleLayer dynamic routing, MI355X. R6: separate kernels (known-good
// structure) + identity conflict-free layout + DMA staging + asum merge +
// 2-i double staging per barrier pair.
// B=32, I=2048, K=16, O=D*A=512 (D=32, A=16), num_routing=3.
//
// Algebra: l2 = sum_a V*(act0+act1), so pass2 == pass1 with asum=act0+act1
// (asum produced by reduce#2 as act1 + act0).
//
// Lane layout: lane owns o = lane*4+j and o = 256+lane*4+j (j=0..3):
//   d1 = lane>>2 (0..15), d2 = d1+16, a = (lane&3)*4+j.
//   a-reduce: shfl_xor {1,2}; softmax-D: e1+e2 then shfl_xor {4,8,16,32}.
// sW row-major (identity) -> global_load_lds 16B DMA staging; hot-loop
// ds_read_b128 at word addr 4*lane -> even 2-way (free) bank pattern.
// Two i's staged per barrier pair (64KB LDS, 2 wgs/CU = 133KB < 160KB).
// x loaded via wave-uniform (SGPR) path.

#define B_  32
#define I_  2048
#define K_  16
#define O_  512
#define NG_ 256   // i-groups (partial leading dim)
#define IC_ 8     // i's per group; grid = NG_*2 (bh split)

typedef const __attribute__((address_space(1))) uint32_t* gp_t;
typedef __attribute__((address_space(3))) uint32_t* lp_t;

template<bool ROUTED>
__global__ __launch_bounds__(256)
void sweep_kernel(const float* __restrict__ x, const float* __restrict__ W,
                  const float* __restrict__ act, float* __restrict__ partial)
{
    const int tid  = threadIdx.x;
    const int lane = tid & 63;
    const int wave = tid >> 6;                  // 0..3
    const int ig   = blockIdx.x >> 1;
    const int bh   = blockIdx.x & 1;
    const int wv    = __builtin_amdgcn_readfirstlane(wave);
    const int bbase = bh * 16 + wv * 4;
    const int ob1  = lane * 4;
    const int ob2  = 256 + lane * 4;

    __shared__ float sW[2 * K_ * O_];           // 64 KB: two W[i] tiles

    float facc[4][8];
    #pragma unroll
    for (int bb = 0; bb < 4; ++bb)
        #pragma unroll
        for (int j = 0; j < 8; ++j) facc[bb][j] = 0.f;

    float as[4][8];
    if (ROUTED) {
        #pragma unroll
        for (int bb = 0; bb < 4; ++bb) {
            const float4 f0 = *(const float4*)(act + (bbase + bb) * O_ + ob1);
            const float4 f1 = *(const float4*)(act + (bbase + bb) * O_ + ob2);
            as[bb][0]=f0.x; as[bb][1]=f0.y; as[bb][2]=f0.z; as[bb][3]=f0.w;
            as[bb][4]=f1.x; as[bb][5]=f1.y; as[bb][6]=f1.z; as[bb][7]=f1.w;
        }
    }

    for (int r = 0; r < IC_ / 2; ++r) {
        const int i0 = ig * IC_ + 2 * r;
        __syncthreads();   // protect prior round's LDS reads
        // stage W[i0], W[i0+1] row-major via 16B direct-to-LDS DMA
        {
            const float* g0 = W + (size_t)i0 * (K_ * O_);
            #pragma unroll
            for (int q = 0; q < 8; ++q) {
                const int c = wave * 8 + q;     // 256-float chunk
                __builtin_amdgcn_global_load_lds(
                    (gp_t)(g0 + c * 256 + lane * 4),
                    (lp_t)(sW + c * 256), 16, 0, 0);
                __builtin_amdgcn_global_load_lds(
                    (gp_t)(g0 + K_ * O_ + c * 256 + lane * 4),
                    (lp_t)(sW + K_ * O_ + c * 256), 16, 0, 0);
            }
        }
        __syncthreads();

        #pragma unroll
        for (int half = 0; half < 2; ++half) {
            const int i = i0 + half;
            const float* buf = sW + half * (K_ * O_);

            // x for this wave's 4 b's: wave-uniform scalar loads
            float xs[4][16];
            #pragma unroll
            for (int bb = 0; bb < 4; ++bb) {
                const float4* xp =
                    (const float4*)(x + ((size_t)(bbase + bb) * I_ + i) * K_);
                #pragma unroll
                for (int q = 0; q < 4; ++q) {
                    float4 v = xp[q];
                    xs[bb][4*q+0]=v.x; xs[bb][4*q+1]=v.y;
                    xs[bb][4*q+2]=v.z; xs[bb][4*q+3]=v.w;
                }
            }

            float V[4][8];
            #pragma unroll
            for (int bb = 0; bb < 4; ++bb)
                #pragma unroll
                for (int j = 0; j < 8; ++j) V[bb][j] = 0.f;
            #pragma unroll
            for (int k = 0; k < K_; ++k) {
                const float4 w0 = *(const float4*)&buf[k * O_ + ob1];
                const float4 w1 = *(const float4*)&buf[k * O_ + ob2];
                #pragma unroll
                for (int bb = 0; bb < 4; ++bb) {
                    const float xb = xs[bb][k];
                    V[bb][0] = fmaf(xb, w0.x, V[bb][0]);
                    V[bb][1] = fmaf(xb, w0.y, V[bb][1]);
                    V[bb][2] = fmaf(xb, w0.z, V[bb][2]);
                    V[bb][3] = fmaf(xb, w0.w, V[bb][3]);
                    V[bb][4] = fmaf(xb, w1.x, V[bb][4]);
                    V[bb][5] = fmaf(xb, w1.y, V[bb][5]);
                    V[bb][6] = fmaf(xb, w1.z, V[bb][6]);
                    V[bb][7] = fmaf(xb, w1.w, V[bb][7]);
                }
            }

            #pragma unroll
            for (int bb = 0; bb < 4; ++bb) {
                if (!ROUTED) {
                    #pragma unroll
                    for (int j = 0; j < 8; ++j) facc[bb][j] += V[bb][j];
                } else {
                    float p1 = 0.f, p2 = 0.f;
                    #pragma unroll
                    for (int j = 0; j < 4; ++j) {
                        p1 = fmaf(V[bb][j],     as[bb][j],     p1);
                        p2 = fmaf(V[bb][j + 4], as[bb][j + 4], p2);
                    }
                    // sum over a: lanes differing in low-2 bits
                    p1 += __shfl_xor(p1, 1);  p1 += __shfl_xor(p1, 2);
                    p2 += __shfl_xor(p2, 1);  p2 += __shfl_xor(p2, 2);
                    // softmax over d=0..31 (d1=lane>>2, d2=d1+16)
                    const float e1 = __expf(p1);
                    const float e2 = __expf(p2);
                    float s = e1 + e2;
                    s += __shfl_xor(s, 4);
                    s += __shfl_xor(s, 8);
                    s += __shfl_xor(s, 16);
                    s += __shfl_xor(s, 32);
                    const float inv = __builtin_amdgcn_rcpf(s);
                    const float r1 = e1 * inv, r2 = e2 * inv;
                    #pragma unroll
                    for (int j = 0; j < 4; ++j) {
                        facc[bb][j]     = fmaf(r1, V[bb][j],     facc[bb][j]);
                        facc[bb][j + 4] = fmaf(r2, V[bb][j + 4], facc[bb][j + 4]);
                    }
                }
            }
        }
    }

    #pragma unroll
    for (int bb = 0; bb < 4; ++bb) {
        const int b = bbase + bb;
        *(float4*)&partial[((size_t)ig * B_ + b) * O_ + ob1] =
            make_float4(facc[bb][0], facc[bb][1], facc[bb][2], facc[bb][3]);
        *(float4*)&partial[((size_t)ig * B_ + b) * O_ + ob2] =
            make_float4(facc[bb][4], facc[bb][5], facc[bb][6], facc[bb][7]);
    }
}

// partial[NG_][B_*O_] summed over NG_, *scale + bias, squash over A;
// dst[g] = squash(...) + (addbase ? addbase[g] : 0).
// 512 wgs x 256 thr; wg covers 32 g's (8 float4) x 32 row-slices of 8.
__global__ __launch_bounds__(256)
void reduce_squash(const float* __restrict__ partial, const float* __restrict__ bias,
                   float scale, const float* __restrict__ addbase,
                   float* __restrict__ dst)
{
    const int t     = threadIdx.x;
    const int gbase = blockIdx.x * 32;
    const int q     = t & 7;        // float4 within the 32 g's
    const int sl    = t >> 3;       // row slice 0..31 (8 rows each)
    const float4* src = (const float4*)partial + (gbase >> 2) + q;

    float4 acc = make_float4(0.f, 0.f, 0.f, 0.f);
    #pragma unroll
    for (int r = 0; r < 8; ++r) {
        float4 v = src[(size_t)(sl * 8 + r) * (B_ * O_ / 4)];
        acc.x += v.x; acc.y += v.y; acc.z += v.z; acc.w += v.w;
    }
    __shared__ float4 red[256];
    red[t] = acc;
    __syncthreads();
    if (t < 32) {
        float v = 0.f;
        #pragma unroll
        for (int s = 0; s < 32; ++s)
            v += ((const float*)&red[s * 8 + (t >> 2)])[t & 3];
        const float p = fmaf(v, scale, bias[(gbase + t) & (O_ - 1)]);
        float nn = p * p;   // squash: norm over 16 a's (low 4 bits of g)
        nn += __shfl_xor(nn, 1);
        nn += __shfl_xor(nn, 2);
        nn += __shfl_xor(nn, 4);
        nn += __shfl_xor(nn, 8);
        float o = p * sqrtf(nn) / (1.f + nn);
        if (addbase) o += addbase[gbase + t];
        dst[gbase + t] = o;
    }
}

extern "C" void kernel_launch(void* const* d_in, const int* in_sizes, int n_in,
                              void* d_out, int out_size, void* d_ws, size_t ws_size,
                              hipStream_t stream) {
    const float* x    = (const float*)d_in[0];   // [32,2048,16]
    const float* W    = (const float*)d_in[1];   // [2048,16,512]
    const float* bias = (const float*)d_in[2];   // [512]
    float* out = (float*)d_out;                  // [32,512]

    float* partial = (float*)d_ws;                       // NG_*32*512 f32 = 16.8 MB
    float* act0    = partial + (size_t)NG_ * B_ * O_;    // 64 KB
    float* asum    = act0 + B_ * O_;                     // 64 KB

    sweep_kernel<false><<<NG_ * 2, 256, 0, stream>>>(x, W, nullptr, partial);
    reduce_squash<<<512, 256, 0, stream>>>(partial, bias, 1.f / 32.f, nullptr, act0);
    sweep_kernel<true><<<NG_ * 2, 256, 0, stream>>>(x, W, act0, partial);
    reduce_squash<<<512, 256, 0, stream>>>(partial, bias, 1.f, act0, asum); // asum=act0+act1
    sweep_kernel<true><<<NG_ * 2, 256, 0, stream>>>(x, W, asum, partial);
    reduce_squash<<<512, 256, 0, stream>>>(partial, bias, 1.f, nullptr, out);
}

// Round 7
// 195.427 us; speedup vs baseline: 1.1930x; 1.1930x over previous
//
#include <hip/hip_runtime.h>

// CapsuleLayer dynamic routing, MI355X. R7: double-buffered DMA pipeline.
// B=32, I=2048, K=16, O=D*A=512 (D=32, A=16), num_routing=3.
//
// R6 bug: DMA -> immediate barrier exposed full HBM latency every round.
// R7: classic 2-buffer pipeline -- at round r, after the barrier, issue the
// DMA for tile r+1 into buf[(r+1)&1], then compute tile r from buf[r&1].
// The next barrier's vmcnt(0) finds the DMA already landed (compute ~3.2k
// cyc/SIMD covers it). One barrier per round. x loads are wave-uniform ->
// s_load (lgkmcnt), independent of the DMA's vmcnt queue.
//
// Algebra: l2 = sum_a V*(act0+act1) -> pass2 == pass1 with asum=act0+act1.
// Lane layout: lane owns o = lane*4+j and o = 256+lane*4+j (j=0..3):
//   d1 = lane>>2 (0..15), d2 = d1+16, a = (lane&3)*4+j.
//   a-reduce: shfl_xor {1,2}; softmax-D: e1+e2 then shfl_xor {4,8,16,32}.
// sW row-major identity -> global_load_lds 16B DMA; ds_read_b128 at word
// addr 4*lane = even 2-way (free) bank pattern.

#define B_  32
#define I_  2048
#define K_  16
#define O_  512
#define KO_ (K_ * O_)
#define NG_ 256   // i-groups (partial leading dim)
#define IC_ 8     // i's per group; grid = NG_*2 (bh split)

typedef const __attribute__((address_space(1))) uint32_t* gp_t;
typedef __attribute__((address_space(3))) uint32_t* lp_t;

__device__ __forceinline__
void stage_tile(const float* __restrict__ g, float* dst, int wave, int lane)
{
    #pragma unroll
    for (int q = 0; q < 8; ++q) {
        const int c = wave * 8 + q;     // 256-float chunk
        __builtin_amdgcn_global_load_lds(
            (gp_t)(g + c * 256 + lane * 4),
            (lp_t)(dst + c * 256), 16, 0, 0);
    }
}

template<bool ROUTED>
__global__ __launch_bounds__(256)
void sweep_kernel(const float* __restrict__ x, const float* __restrict__ W,
                  const float* __restrict__ act, float* __restrict__ partial)
{
    const int tid  = threadIdx.x;
    const int lane = tid & 63;
    const int wave = tid >> 6;                  // 0..3
    const int ig   = blockIdx.x >> 1;
    const int bh   = blockIdx.x & 1;
    const int wv    = __builtin_amdgcn_readfirstlane(wave);
    const int bbase = bh * 16 + wv * 4;
    const int ob1  = lane * 4;
    const int ob2  = 256 + lane * 4;
    const int ibase = ig * IC_;

    __shared__ float sW[2 * KO_];               // 64 KB: double buffer

    // prefetch tile 0 before anything else
    stage_tile(W + (size_t)ibase * KO_, sW, wave, lane);

    float facc[4][8];
    #pragma unroll
    for (int bb = 0; bb < 4; ++bb)
        #pragma unroll
        for (int j = 0; j < 8; ++j) facc[bb][j] = 0.f;

    float as[4][8];
    if (ROUTED) {
        #pragma unroll
        for (int bb = 0; bb < 4; ++bb) {
            const float4 f0 = *(const float4*)(act + (bbase + bb) * O_ + ob1);
            const float4 f1 = *(const float4*)(act + (bbase + bb) * O_ + ob2);
            as[bb][0]=f0.x; as[bb][1]=f0.y; as[bb][2]=f0.z; as[bb][3]=f0.w;
            as[bb][4]=f1.x; as[bb][5]=f1.y; as[bb][6]=f1.z; as[bb][7]=f1.w;
        }
    }

    for (int r = 0; r < IC_; ++r) {
        const int i = ibase + r;
        __syncthreads();   // vmcnt(0): buf[r&1] landed; prev round's reads done
        if (r + 1 < IC_)   // overlap next tile's DMA with this round's compute
            stage_tile(W + (size_t)(i + 1) * KO_, sW + ((r + 1) & 1) * KO_,
                       wave, lane);

        // x for this wave's 4 b's: wave-uniform scalar loads (lgkmcnt path)
        float xs[4][16];
        #pragma unroll
        for (int bb = 0; bb < 4; ++bb) {
            const float4* xp =
                (const float4*)(x + ((size_t)(bbase + bb) * I_ + i) * K_);
            #pragma unroll
            for (int q = 0; q < 4; ++q) {
                float4 v = xp[q];
                xs[bb][4*q+0]=v.x; xs[bb][4*q+1]=v.y;
                xs[bb][4*q+2]=v.z; xs[bb][4*q+3]=v.w;
            }
        }

        const float* buf = sW + (r & 1) * KO_;
        float V[4][8];
        #pragma unroll
        for (int bb = 0; bb < 4; ++bb)
            #pragma unroll
            for (int j = 0; j < 8; ++j) V[bb][j] = 0.f;
        #pragma unroll
        for (int k = 0; k < K_; ++k) {
            const float4 w0 = *(const float4*)&buf[k * O_ + ob1];
            const float4 w1 = *(const float4*)&buf[k * O_ + ob2];
            #pragma unroll
            for (int bb = 0; bb < 4; ++bb) {
                const float xb = xs[bb][k];
                V[bb][0] = fmaf(xb, w0.x, V[bb][0]);
                V[bb][1] = fmaf(xb, w0.y, V[bb][1]);
                V[bb][2] = fmaf(xb, w0.z, V[bb][2]);
                V[bb][3] = fmaf(xb, w0.w, V[bb][3]);
                V[bb][4] = fmaf(xb, w1.x, V[bb][4]);
                V[bb][5] = fmaf(xb, w1.y, V[bb][5]);
                V[bb][6] = fmaf(xb, w1.z, V[bb][6]);
                V[bb][7] = fmaf(xb, w1.w, V[bb][7]);
            }
        }

        #pragma unroll
        for (int bb = 0; bb < 4; ++bb) {
            if (!ROUTED) {
                #pragma unroll
                for (int j = 0; j < 8; ++j) facc[bb][j] += V[bb][j];
            } else {
                float p1 = 0.f, p2 = 0.f;
                #pragma unroll
                for (int j = 0; j < 4; ++j) {
                    p1 = fmaf(V[bb][j],     as[bb][j],     p1);
                    p2 = fmaf(V[bb][j + 4], as[bb][j + 4], p2);
                }
                // sum over a: lanes differing in low-2 bits
                p1 += __shfl_xor(p1, 1);  p1 += __shfl_xor(p1, 2);
                p2 += __shfl_xor(p2, 1);  p2 += __shfl_xor(p2, 2);
                // softmax over d=0..31 (d1=lane>>2, d2=d1+16); logits small
                const float e1 = __expf(p1);
                const float e2 = __expf(p2);
                float s = e1 + e2;
                s += __shfl_xor(s, 4);
                s += __shfl_xor(s, 8);
                s += __shfl_xor(s, 16);
                s += __shfl_xor(s, 32);
                const float inv = __builtin_amdgcn_rcpf(s);
                const float r1 = e1 * inv, r2 = e2 * inv;
                #pragma unroll
                for (int j = 0; j < 4; ++j) {
                    facc[bb][j]     = fmaf(r1, V[bb][j],     facc[bb][j]);
                    facc[bb][j + 4] = fmaf(r2, V[bb][j + 4], facc[bb][j + 4]);
                }
            }
        }
    }

    #pragma unroll
    for (int bb = 0; bb < 4; ++bb) {
        const int b = bbase + bb;
        *(float4*)&partial[((size_t)ig * B_ + b) * O_ + ob1] =
            make_float4(facc[bb][0], facc[bb][1], facc[bb][2], facc[bb][3]);
        *(float4*)&partial[((size_t)ig * B_ + b) * O_ + ob2] =
            make_float4(facc[bb][4], facc[bb][5], facc[bb][6], facc[bb][7]);
    }
}

// partial[NG_][B_*O_] summed over NG_, *scale + bias, squash over A;
// dst[g] = squash(...) + (addbase ? addbase[g] : 0).
// 512 wgs x 256 thr; wg covers 32 g's (8 float4) x 32 row-slices of 8.
__global__ __launch_bounds__(256)
void reduce_squash(const float* __restrict__ partial, const float* __restrict__ bias,
                   float scale, const float* __restrict__ addbase,
                   float* __restrict__ dst)
{
    const int t     = threadIdx.x;
    const int gbase = blockIdx.x * 32;
    const int q     = t & 7;        // float4 within the 32 g's
    const int sl    = t >> 3;       // row slice 0..31 (8 rows each)
    const float4* src = (const float4*)partial + (gbase >> 2) + q;

    float4 acc = make_float4(0.f, 0.f, 0.f, 0.f);
    #pragma unroll
    for (int r = 0; r < 8; ++r) {
        float4 v = src[(size_t)(sl * 8 + r) * (B_ * O_ / 4)];
        acc.x += v.x; acc.y += v.y; acc.z += v.z; acc.w += v.w;
    }
    __shared__ float4 red[256];
    red[t] = acc;
    __syncthreads();
    if (t < 32) {
        float v = 0.f;
        #pragma unroll
        for (int s = 0; s < 32; ++s)
            v += ((const float*)&red[s * 8 + (t >> 2)])[t & 3];
        const float p = fmaf(v, scale, bias[(gbase + t) & (O_ - 1)]);
        float nn = p * p;   // squash: norm over 16 a's (low 4 bits of g)
        nn += __shfl_xor(nn, 1);
        nn += __shfl_xor(nn, 2);
        nn += __shfl_xor(nn, 4);
        nn += __shfl_xor(nn, 8);
        float o = p * sqrtf(nn) / (1.f + nn);
        if (addbase) o += addbase[gbase + t];
        dst[gbase + t] = o;
    }
}

extern "C" void kernel_launch(void* const* d_in, const int* in_sizes, int n_in,
                              void* d_out, int out_size, void* d_ws, size_t ws_size,
                              hipStream_t stream) {
    const float* x    = (const float*)d_in[0];   // [32,2048,16]
    const float* W    = (const float*)d_in[1];   // [2048,16,512]
    const float* bias = (const float*)d_in[2];   // [512]
    float* out = (float*)d_out;                  // [32,512]

    float* partial = (float*)d_ws;                       // NG_*32*512 f32 = 16.8 MB
    float* act0    = partial + (size_t)NG_ * B_ * O_;    // 64 KB
    float* asum    = act0 + B_ * O_;                     // 64 KB

    sweep_kernel<false><<<NG_ * 2, 256, 0, stream>>>(x, W, nullptr, partial);
    reduce_squash<<<512, 256, 0, stream>>>(partial, bias, 1.f / 32.f, nullptr, act0);
    sweep_kernel<true><<<NG_ * 2, 256, 0, stream>>>(x, W, act0, partial);
    reduce_squash<<<512, 256, 0, stream>>>(partial, bias, 1.f, act0, asum); // asum=act0+act1
    sweep_kernel<true><<<NG_ * 2, 256, 0, stream>>>(x, W, asum, partial);
    reduce_squash<<<512, 256, 0, stream>>>(partial, bias, 1.f, nullptr, out);
}

// Round 8
// 194.603 us; speedup vs baseline: 1.1980x; 1.0042x over previous
//
#include <hip/hip_runtime.h>

// CapsuleLayer dynamic routing, MI355X. R8: barrier-free W streaming.
// B=32, I=2048, K=16, O=D*A=512 (D=32, A=16), num_routing=3.
//
// R7 lesson: LDS staging buys no reuse L1/L2 can't provide (4 waves/wg +
// bh-twin wg all read the same 32KB tile; L2 serves it), but costs a
// barrier+vmcnt(0) drain per tile and the whole LDS pipe. R8 streams W
// straight to VGPRs: lane reads exactly its 8 floats per k via two
// coalesced global_load_dwordx4 (64 lanes x lane*16B = 1KB segments),
// software-pipelined in 4-k chunks (8 loads in flight). No LDS, no
// barriers; waves fully independent.
//
// Algebra: l2 = sum_a V*(act0+act1) -> pass2 == pass1 with asum=act0+act1.
// Lane layout: lane owns o = lane*4+j and o = 256+lane*4+j (j=0..3):
//   d1 = lane>>2 (0..15), d2 = d1+16, a = (lane&3)*4+j.
//   a-reduce: shfl_xor {1,2}; softmax-D: e1+e2 then shfl_xor {4,8,16,32}.
// x loads stay wave-uniform (s_load path).

#define B_  32
#define I_  2048
#define K_  16
#define O_  512
#define KO_ (K_ * O_)
#define NG_ 256   // i-groups (partial leading dim)
#define IC_ 8     // i's per group; grid = NG_*2 (bh split)

template<bool ROUTED>
__global__ __launch_bounds__(256)
void sweep_kernel(const float* __restrict__ x, const float* __restrict__ W,
                  const float* __restrict__ act, float* __restrict__ partial)
{
    const int tid  = threadIdx.x;
    const int lane = tid & 63;
    const int wave = tid >> 6;                  // 0..3
    const int ig   = blockIdx.x >> 1;
    const int bh   = blockIdx.x & 1;
    const int wv    = __builtin_amdgcn_readfirstlane(wave);
    const int bbase = bh * 16 + wv * 4;
    const int ob1  = lane * 4;
    const int ob2  = 256 + lane * 4;
    const int ibase = ig * IC_;

    float facc[4][8];
    #pragma unroll
    for (int bb = 0; bb < 4; ++bb)
        #pragma unroll
        for (int j = 0; j < 8; ++j) facc[bb][j] = 0.f;

    float as[4][8];
    if (ROUTED) {
        #pragma unroll
        for (int bb = 0; bb < 4; ++bb) {
            const float4 f0 = *(const float4*)(act + (bbase + bb) * O_ + ob1);
            const float4 f1 = *(const float4*)(act + (bbase + bb) * O_ + ob2);
            as[bb][0]=f0.x; as[bb][1]=f0.y; as[bb][2]=f0.z; as[bb][3]=f0.w;
            as[bb][4]=f1.x; as[bb][5]=f1.y; as[bb][6]=f1.z; as[bb][7]=f1.w;
        }
    }

    // W as float4: element (i,k,half) at wp4[i*2048 + k*128 + half*64 + lane]
    const float4* wp4 = (const float4*)W + (size_t)ibase * (KO_ / 4) + lane;

    // k-chunk pipeline: chunk = 4 k's x 2 halves = 8 float4 in flight
    float4 wreg[2][8];
    #pragma unroll
    for (int u = 0; u < 4; ++u) {               // preload chunk 0 of i=ibase
        wreg[0][2*u]   = wp4[u * 128];
        wreg[0][2*u+1] = wp4[u * 128 + 64];
    }

    for (int ii = 0; ii < IC_; ++ii) {
        const int i = ibase + ii;
        const float4* wcur  = wp4 + (size_t)ii * 2048;

        // x for this wave's 4 b's: wave-uniform scalar loads
        float xs[4][16];
        #pragma unroll
        for (int bb = 0; bb < 4; ++bb) {
            const float4* xp =
                (const float4*)(x + ((size_t)(bbase + bb) * I_ + i) * K_);
            #pragma unroll
            for (int q = 0; q < 4; ++q) {
                float4 v = xp[q];
                xs[bb][4*q+0]=v.x; xs[bb][4*q+1]=v.y;
                xs[bb][4*q+2]=v.z; xs[bb][4*q+3]=v.w;
            }
        }

        float V[4][8];
        #pragma unroll
        for (int bb = 0; bb < 4; ++bb)
            #pragma unroll
            for (int j = 0; j < 8; ++j) V[bb][j] = 0.f;

        #pragma unroll
        for (int c = 0; c < 4; ++c) {           // 4 chunks of 4 k's
            const int cur = c & 1, nxt = cur ^ 1;
            // issue next chunk's loads (next i's chunk 0 when c==3)
            if (c < 3) {
                #pragma unroll
                for (int u = 0; u < 4; ++u) {
                    wreg[nxt][2*u]   = wcur[(c+1) * 4 * 128 + u * 128];
                    wreg[nxt][2*u+1] = wcur[(c+1) * 4 * 128 + u * 128 + 64];
                }
            } else if (ii + 1 < IC_) {
                #pragma unroll
                for (int u = 0; u < 4; ++u) {
                    wreg[nxt][2*u]   = wcur[2048 + u * 128];
                    wreg[nxt][2*u+1] = wcur[2048 + u * 128 + 64];
                }
            }
            // FMA on current chunk (k = c*4 .. c*4+3)
            #pragma unroll
            for (int u = 0; u < 4; ++u) {
                const float4 w0 = wreg[cur][2*u];
                const float4 w1 = wreg[cur][2*u+1];
                const int k = c * 4 + u;
                #pragma unroll
                for (int bb = 0; bb < 4; ++bb) {
                    const float xb = xs[bb][k];
                    V[bb][0] = fmaf(xb, w0.x, V[bb][0]);
                    V[bb][1] = fmaf(xb, w0.y, V[bb][1]);
                    V[bb][2] = fmaf(xb, w0.z, V[bb][2]);
                    V[bb][3] = fmaf(xb, w0.w, V[bb][3]);
                    V[bb][4] = fmaf(xb, w1.x, V[bb][4]);
                    V[bb][5] = fmaf(xb, w1.y, V[bb][5]);
                    V[bb][6] = fmaf(xb, w1.z, V[bb][6]);
                    V[bb][7] = fmaf(xb, w1.w, V[bb][7]);
                }
            }
        }

        #pragma unroll
        for (int bb = 0; bb < 4; ++bb) {
            if (!ROUTED) {
                #pragma unroll
                for (int j = 0; j < 8; ++j) facc[bb][j] += V[bb][j];
            } else {
                float p1 = 0.f, p2 = 0.f;
                #pragma unroll
                for (int j = 0; j < 4; ++j) {
                    p1 = fmaf(V[bb][j],     as[bb][j],     p1);
                    p2 = fmaf(V[bb][j + 4], as[bb][j + 4], p2);
                }
                // sum over a: lanes differing in low-2 bits
                p1 += __shfl_xor(p1, 1);  p1 += __shfl_xor(p1, 2);
                p2 += __shfl_xor(p2, 1);  p2 += __shfl_xor(p2, 2);
                // softmax over d=0..31 (d1=lane>>2, d2=d1+16); logits small
                const float e1 = __expf(p1);
                const float e2 = __expf(p2);
                float s = e1 + e2;
                s += __shfl_xor(s, 4);
                s += __shfl_xor(s, 8);
                s += __shfl_xor(s, 16);
                s += __shfl_xor(s, 32);
                const float inv = __builtin_amdgcn_rcpf(s);
                const float r1 = e1 * inv, r2 = e2 * inv;
                #pragma unroll
                for (int j = 0; j < 4; ++j) {
                    facc[bb][j]     = fmaf(r1, V[bb][j],     facc[bb][j]);
                    facc[bb][j + 4] = fmaf(r2, V[bb][j + 4], facc[bb][j + 4]);
                }
            }
        }
    }

    #pragma unroll
    for (int bb = 0; bb < 4; ++bb) {
        const int b = bbase + bb;
        *(float4*)&partial[((size_t)ig * B_ + b) * O_ + ob1] =
            make_float4(facc[bb][0], facc[bb][1], facc[bb][2], facc[bb][3]);
        *(float4*)&partial[((size_t)ig * B_ + b) * O_ + ob2] =
            make_float4(facc[bb][4], facc[bb][5], facc[bb][6], facc[bb][7]);
    }
}

// partial[NG_][B_*O_] summed over NG_, *scale + bias, squash over A;
// dst[g] = squash(...) + (addbase ? addbase[g] : 0).
// 512 wgs x 256 thr; wg covers 32 g's (8 float4) x 32 row-slices of 8.
__global__ __launch_bounds__(256)
void reduce_squash(const float* __restrict__ partial, const float* __restrict__ bias,
                   float scale, const float* __restrict__ addbase,
                   float* __restrict__ dst)
{
    const int t     = threadIdx.x;
    const int gbase = blockIdx.x * 32;
    const int q     = t & 7;        // float4 within the 32 g's
    const int sl    = t >> 3;       // row slice 0..31 (8 rows each)
    const float4* src = (const float4*)partial + (gbase >> 2) + q;

    float4 acc = make_float4(0.f, 0.f, 0.f, 0.f);
    #pragma unroll
    for (int r = 0; r < 8; ++r) {
        float4 v = src[(size_t)(sl * 8 + r) * (B_ * O_ / 4)];
        acc.x += v.x; acc.y += v.y; acc.z += v.z; acc.w += v.w;
    }
    __shared__ float4 red[256];
    red[t] = acc;
    __syncthreads();
    if (t < 32) {
        float v = 0.f;
        #pragma unroll
        for (int s = 0; s < 32; ++s)
            v += ((const float*)&red[s * 8 + (t >> 2)])[t & 3];
        const float p = fmaf(v, scale, bias[(gbase + t) & (O_ - 1)]);
        float nn = p * p;   // squash: norm over 16 a's (low 4 bits of g)
        nn += __shfl_xor(nn, 1);
        nn += __shfl_xor(nn, 2);
        nn += __shfl_xor(nn, 4);
        nn += __shfl_xor(nn, 8);
        float o = p * sqrtf(nn) / (1.f + nn);
        if (addbase) o += addbase[gbase + t];
        dst[gbase + t] = o;
    }
}

extern "C" void kernel_launch(void* const* d_in, const int* in_sizes, int n_in,
                              void* d_out, int out_size, void* d_ws, size_t ws_size,
                              hipStream_t stream) {
    const float* x    = (const float*)d_in[0];   // [32,2048,16]
    const float* W    = (const float*)d_in[1];   // [2048,16,512]
    const float* bias = (const float*)d_in[2];   // [512]
    float* out = (float*)d_out;                  // [32,512]

    float* partial = (float*)d_ws;                       // NG_*32*512 f32 = 16.8 MB
    float* act0    = partial + (size_t)NG_ * B_ * O_;    // 64 KB
    float* asum    = act0 + B_ * O_;                     // 64 KB

    sweep_kernel<false><<<NG_ * 2, 256, 0, stream>>>(x, W, nullptr, partial);
    reduce_squash<<<512, 256, 0, stream>>>(partial, bias, 1.f / 32.f, nullptr, act0);
    sweep_kernel<true><<<NG_ * 2, 256, 0, stream>>>(x, W, act0, partial);
    reduce_squash<<<512, 256, 0, stream>>>(partial, bias, 1.f, act0, asum); // asum=act0+act1
    sweep_kernel<true><<<NG_ * 2, 256, 0, stream>>>(x, W, asum, partial);
    reduce_squash<<<512, 256, 0, stream>>>(partial, bias, 1.f, nullptr, out);
}